// Round 7
// baseline (455.831 us; speedup 1.0000x reference)
//
#include <hip/hip_runtime.h>
#include <hip/hip_bf16.h>

// StochasticTernaryLinear: out = x @ ((sign(wp)-sign(wn))*0.5).T + bias
// B=524288, IN_F=128, OUT_F=128, fp32 in/out.
// R7: persistent barrier-free streaming GEMM.
//  - 512 blocks = exactly 2 blocks/CU, each wave owns 16 contiguous 16-row
//    tiles (2048 waves x 256 rows = B). Weights staged to LDS once
//    (global_load_lds 16B, fragment-ordered), ONE __syncthreads total.
//  - per tile: prefetch next tile into ping-pong regs (static idx via full
//    unroll), cvt + 32 MFMA from LDS ds_read_b128, store dwordx4.
//  - acc initialized from bias (MFMA C-in) -> epilogue is pure stores.
// R5 counters showed latency-bound phase-lockstep (2.4 TB/s, all pipes idle);
// this keeps loads in flight continuously across desynchronized waves.

typedef short short8 __attribute__((ext_vector_type(8)));
typedef float f32x4 __attribute__((ext_vector_type(4)));
typedef float f32x8 __attribute__((ext_vector_type(8)));

// fp32 -> bf16 bits, round-to-nearest-even (inputs are finite normals)
__device__ __forceinline__ short f2bf(float f) {
  unsigned u = __builtin_bit_cast(unsigned, f);
  unsigned r = u + 0x7fffu + ((u >> 16) & 1u);
  return (short)(r >> 16);
}

// Emit ternary weights in MFMA A-fragment order:
// wfrag[chunk*64 + lane], chunk = kk*8 + c, holds
// w[outcol = c*16 + (lane&15)][k = kk*32 + (lane>>4)*8 + j], j=0..7.
__global__ void ternarize_frag_kernel(const float* __restrict__ wp,
                                      const float* __restrict__ wn,
                                      short8* __restrict__ wfrag) {
  const int tid = blockIdx.x * blockDim.x + threadIdx.x;  // 0..2047
  const int lane = tid & 63;
  const int chunk = tid >> 6;  // kk*8 + c
  const int kk = chunk >> 3, c = chunk & 7;
  const int r = lane & 15, g = lane >> 4;
  const int outcol = c * 16 + r;
  const int k0 = kk * 32 + g * 8;
  const float* p = wp + outcol * 128 + k0;
  const float* q = wn + outcol * 128 + k0;
  short8 v;
#pragma unroll
  for (int j = 0; j < 8; ++j) {
    float s = 0.5f * ((p[j] >= 0.f ? 1.f : -1.f) - (q[j] >= 0.f ? 1.f : -1.f));
    v[j] = f2bf(s);  // exactly -1, 0, +1 in bf16
  }
  wfrag[tid] = v;
}

// MFMA 16x16x32 bf16: A = weight frag (M = out-cols), B = x frag (N = rows).
// D: col(N) = lane&15 -> x-row r, row(M) = (lane>>4)*4 + reg -> out-col
// g*4+reg. Verified absmax 0.25 in R5/R6.
__launch_bounds__(256, 2)
__global__ void stl_gemm_kernel(const float* __restrict__ x,
                                const short8* __restrict__ wfrag,
                                const float* __restrict__ bias,
                                float* __restrict__ out) {
  __shared__ short8 wlds[2048];  // 32 KB, fragment-ordered, linear
  const int tid = threadIdx.x;
  const int wave = tid >> 6;
  const int lane = tid & 63;
  const int r = lane & 15;
  const int g = lane >> 4;

  // Stage weights global->LDS once (linear dest == lane order).
#pragma unroll
  for (int i = 0; i < 8; ++i) {
    const int chunk = i * 256 + tid;
    __builtin_amdgcn_global_load_lds(
        (const __attribute__((address_space(1))) void*)(wfrag + chunk),
        (__attribute__((address_space(3))) void*)(wlds + chunk),
        16, 0, 0);
  }

  // Bias fragments: out-cols c*16 + g*4 .. +3 (L2-hot).
  f32x4 bv[8];
#pragma unroll
  for (int c = 0; c < 8; ++c) bv[c] = *(const f32x4*)(bias + c * 16 + g * 4);

  __syncthreads();  // the ONLY barrier: wlds ready

  // Persistent tiling: wave wid owns 16 contiguous 16-row tiles.
  const int wid = blockIdx.x * 4 + wave;  // 0..2047
  const long row_base = (long)wid * 256;
  const float* xp = x + (row_base + r) * 128 + g * 8;
  float* op = out + (row_base + r) * 128;

  f32x8 xbuf[2][4];  // ping-pong; full unroll -> static indices
#pragma unroll
  for (int kk = 0; kk < 4; ++kk) xbuf[0][kk] = *(const f32x8*)(xp + kk * 32);

#pragma unroll
  for (int t = 0; t < 16; ++t) {
    const int cur = t & 1;  // compile-time after unroll
    // Prefetch next tile into the other buffer (8 dwordx4 in flight).
    if (t < 15) {
      const float* xn = xp + (t + 1) * 2048;  // +16 rows
#pragma unroll
      for (int kk = 0; kk < 4; ++kk)
        xbuf[cur ^ 1][kk] = *(const f32x8*)(xn + kk * 32);
      __builtin_amdgcn_sched_barrier(0);  // don't sink the prefetch
    }

    f32x4 acc[8];
#pragma unroll
    for (int c = 0; c < 8; ++c) acc[c] = bv[c];  // bias as MFMA C-in
#pragma unroll
    for (int kk = 0; kk < 4; ++kk) {
      short8 bx;
#pragma unroll
      for (int j = 0; j < 8; ++j) bx[j] = f2bf(xbuf[cur][kk][j]);
#pragma unroll
      for (int c = 0; c < 8; ++c) {
        const short8 aw = wlds[(kk * 8 + c) * 64 + lane];  // ds_read_b128
        acc[c] = __builtin_amdgcn_mfma_f32_16x16x32_bf16(aw, bx, acc[c], 0, 0, 0);
      }
    }

    float* ot = op + (long)t * 2048;  // row = row_base + t*16 + r
#pragma unroll
    for (int c = 0; c < 8; ++c)
      *(f32x4*)(ot + c * 16 + g * 4) = acc[c];
  }
}

extern "C" void kernel_launch(void* const* d_in, const int* in_sizes, int n_in,
                              void* d_out, int out_size, void* d_ws, size_t ws_size,
                              hipStream_t stream) {
  const float* x    = (const float*)d_in[0];
  const float* wp   = (const float*)d_in[1];
  const float* wn   = (const float*)d_in[2];
  const float* bias = (const float*)d_in[3];
  float* out = (float*)d_out;
  short8* wfrag = (short8*)d_ws;  // 2048 frags * 16 B = 32 KB scratch

  ternarize_frag_kernel<<<8, 256, 0, stream>>>(wp, wn, wfrag);

  // 512 blocks = 2 per CU, persistent; 2048 waves x 256 rows = 524288.
  stl_gemm_kernel<<<512, 256, 0, stream>>>(x, wfrag, bias, out);
}